// Round 9
// baseline (280.323 us; speedup 1.0000x reference)
//
#include <hip/hip_runtime.h>

// ROI Align (max) — R12: R11 plane-streaming, ring off-by-one fixed.
//
// R11 failed correctness: ring=64 rows (77824 B) streamed as 76x1024B
// chunks; rows (1216 B) aren't chunk-aligned, so the last 76 chunks only
// fully cover the last *63* rows — the newest partial chunk aliases the
// head of the oldest row (= yfA, which IS read). Also the in-flight B
// prefetch (cap yfA+64) could overwrite row yfA's head during A's compute.
// Exact lemma: rows [loadedT-63, loadedT) fully resident; prefetch to
// tgt<=yf+63 overwrites only rows <= tgt-64 <= yf-1. Fix: WIN=63 in the
// COLLECT fit rule and both prefetch caps. Max box span ~51 rows < 63.
//
// Structure (unchanged): block=(channel,batch) streams its whole plane
// once, sequentially, via global_load_lds through a 64-row LDS ring;
// y-sorted boxes (rank kernel) computed in groups of <=5 as the window
// slides. Every feature byte staged once, serves ~50 box-cells.
// Out writes XCD-aligned: c=(bid&7)*32 + bid>>4.
//
// feature: (2, 256, 200, 304) fp32; boxes: (512,4); batch_idx: (512,) i32
// out: (512, 256, 7, 7) fp32. SPATIAL_SCALE=0.25, POOLED=7, SR=2, MODE=max.

#define SS 0.25f
#define POOLED 7

constexpr int Cc = 256;
constexpr int Hc = 200;
constexpr int Wc = 304;
constexpr int Nc = 512;

constexpr int CELLS   = 49;
constexpr int PER_BOX = Cc * CELLS;          // 12544
constexpr int PLANE   = Hc * Wc;             // 60800
constexpr int PLANE_B = PLANE * 4;           // 243200
constexpr int RING_ROWS = 64;                // ring modulo (rows)
constexpr int WIN     = 63;                  // usable window rows (chunk math)
constexpr int RING_F  = RING_ROWS * Wc;      // 19456 floats
constexpr int RING_B  = RING_F * 4;          // 77824 B -> 2 blocks/CU
constexpr int RING_CH = RING_B / 1024;       // 76 chunks per ring cycle
constexpr int G   = 5;                       // boxes per compute group
constexpr int NS  = 14;                      // samples per axis

// ---- workspace layout ----
constexpr int    TBL_OFF_B     = 2048;       // after meta[512] u32
constexpr int    TBL_STRIDE_I4 = 28;         // 14 y-recs + 14 x-recs (int4)
constexpr size_t WS_NEED = TBL_OFF_B + (size_t)Nc * TBL_STRIDE_I4 * 16;

// ======================= prep: rank + tables =========================
__global__ __launch_bounds__(64) void roi_prep_kernel(
    const float* __restrict__ boxes,
    const int*   __restrict__ batch_idx,
    unsigned int* __restrict__ meta,
    int4*        __restrict__ tbl)
{
    const int n = blockIdx.x, l = threadIdx.x;

    const float rsx = boxes[n*4+0]*SS, rsy = boxes[n*4+1]*SS;
    const float rex = boxes[n*4+2]*SS, rey = boxes[n*4+3]*SS;
    const float bin_h = fmaxf(rey - rsy, 1.0f) / (float)POOLED;
    const float bin_w = fmaxf(rex - rsx, 1.0f) / (float)POOLED;
    const int   batch = batch_idx[n];

    // y-range (uniform): ymin = row of first sample, ymax = y1 of last
    const float fy0 = __fadd_rn(rsy, __fmul_rn(0.25f, bin_h));
    const int y0min = (int)floorf(fminf(fmaxf(fy0, 0.f), (float)(Hc-1)));
    const float fyL = __fadd_rn(rsy, __fmul_rn(6.75f, bin_h));
    const int   yL  = (int)floorf(fminf(fmaxf(fyL, 0.f), (float)(Hc-1)));
    const int ymax  = min(yL + 1, Hc - 1);
    const unsigned key = (unsigned)(batch * 256 + y0min);

    // bijective rank by (batch, ymin, n) via ballot
    int rank = 0;
    #pragma unroll
    for (int m = 0; m < Nc/64; ++m) {
        const int j = m*64 + l;
        const float rsyj = boxes[j*4+1]*SS, reyj = boxes[j*4+3]*SS;
        const float bhj  = fmaxf(reyj - rsyj, 1.0f) / (float)POOLED;
        const float fyj  = __fadd_rn(rsyj, __fmul_rn(0.25f, bhj));
        const int   yj   = (int)floorf(fminf(fmaxf(fyj,0.f),(float)(Hc-1)));
        const unsigned keyj = (unsigned)(batch_idx[j]*256 + yj);
        const bool lt = (keyj < key) || (keyj == key && j < n);
        rank += (int)__popcll(__ballot(lt));
    }
    if (l == 0)
        meta[rank] = (unsigned)n | ((unsigned)batch << 9)
                   | ((unsigned)y0min << 10) | ((unsigned)ymax << 18);

    // factorized sample tables (validity folded into zeroed weights)
    if (l < NS) {
        const float py  = fmaf((float)l, 0.5f, 0.25f);
        const float fy  = __fadd_rn(rsy, __fmul_rn(py, bin_h));
        const bool  vy  = (fy > -1.0f) && (fy < (float)Hc);
        const float fyc = fminf(fmaxf(fy, 0.f), (float)(Hc-1));
        const int   y0  = (int)floorf(fyc);
        const float ly  = fyc - (float)y0, hy = 1.0f - ly;
        int4 r; r.x = y0;
        r.y = __float_as_int(vy ? hy : 0.0f);
        r.z = __float_as_int(vy ? ly : 0.0f); r.w = 0;
        tbl[n*TBL_STRIDE_I4 + l] = r;
    } else if (l >= 16 && l < 16 + NS) {
        const int s = l - 16;
        const float px  = fmaf((float)s, 0.5f, 0.25f);
        const float fx  = __fadd_rn(rsx, __fmul_rn(px, bin_w));
        const bool  vx  = (fx > -1.0f) && (fx < (float)Wc);
        const float fxc = fminf(fmaxf(fx, 0.f), (float)(Wc-1));
        const int   x0  = (int)floorf(fxc);
        const float lx  = fxc - (float)x0, hx = 1.0f - lx;
        int4 r; r.x = x0;
        r.y = __float_as_int(vx ? hx : 0.0f);
        r.z = __float_as_int(vx ? lx : 0.0f); r.w = 0;
        tbl[n*TBL_STRIDE_I4 + NS + s] = r;
    }
}

// ============================ main ===================================
__global__ __launch_bounds__(256) void roi_stream_kernel(
    const float* __restrict__ feature,
    const unsigned int* __restrict__ meta,
    const int4*  __restrict__ tbl,
    float*       __restrict__ out)
{
    __shared__ float ring[RING_F];           // 77,824 B -> 2 blocks/CU

    const int bid = blockIdx.x;
    const int X = bid & 7, b = (bid >> 3) & 1, cj = bid >> 4;
    const int c = X * 32 + cj;               // XCD X owns channels [32X,32X+32)
    const char* __restrict__ plane =
        (const char*)(feature + ((size_t)b * Cc + c) * (size_t)PLANE);

    const int tid = threadIdx.x, wv = tid >> 6, lane = tid & 63;
    const int bg   = tid / CELLS;            // 0..5
    const int cell = tid - bg * CELLS;
    const int ph   = cell / POOLED, pw = cell - ph * POOLED;
    const bool hasCell = (tid < G * CELLS);  // 245 compute threads

    int p = 0, loadedT = 0;

    int cntA=0, yfA=0, tmA=0, nA0=0,nA1=0,nA2=0,nA3=0,nA4=0;
    int cntB=0, yfB=0, tmB=0, nB0=0,nB1=0,nB2=0,nB3=0,nB4=0;
    int4 ya0, ya1, xa0, xa1, yb0, yb1, xb0, xb1;

#define COLLECT(CNT,YF,TM,N0,N1,N2,N3,N4) {                                  \
    CNT = 0; YF = 0; TM = 0;                                                 \
    while (p < Nc) {                                                         \
        const unsigned mm = meta[p];                                         \
        const int bt = (int)((mm >> 9) & 1u);                                \
        if (bt != b) { if (bt < b) { ++p; continue; } else break; }          \
        const int ymin = (int)((mm >> 10) & 255u);                           \
        const int ymx  = (int)((mm >> 18) & 255u);                           \
        const int nn   = (int)(mm & 511u);                                   \
        if (CNT == 0) { YF = ymin; N0 = N1 = N2 = N3 = N4 = nn; }            \
        else if (ymx + 1 > YF + WIN) break;                                  \
        if      (CNT == 1) N1 = nn; else if (CNT == 2) N2 = nn;              \
        else if (CNT == 3) N3 = nn; else if (CNT == 4) N4 = nn;              \
        TM = max(TM, ymx + 1);                                               \
        ++CNT; ++p;                                                          \
        if (CNT == G) break;                                                 \
    }                                                                        \
}

#define ISSUE(FROMT, TOT) {                                                  \
    const int kc0 = (19*(FROMT) + 15) >> 4, kc1 = (19*(TOT) + 15) >> 4;      \
    for (int k = kc0 + ((wv - kc0) & 3); k < kc1; k += 4) {                  \
        const int km  = k % RING_CH;                                         \
        const int off = k * 1024 + lane * 16;                                \
        if (off < PLANE_B) {                                                 \
            const int ldst = __builtin_amdgcn_readfirstlane(km * 1024);      \
            __builtin_amdgcn_global_load_lds(                                \
                (const __attribute__((address_space(1))) unsigned int*)      \
                    (const void*)(plane + off),                              \
                (__attribute__((address_space(3))) unsigned int*)            \
                    (void*)((char*)ring + ldst), 16, 0, 0);                  \
        }                                                                    \
    }                                                                        \
}

#define LOADREC(N0,N1,N2,N3,N4, Y0,Y1,X0,X1) {                               \
    const int nSel = (bg==0)?(N0):(bg==1)?(N1):(bg==2)?(N2):(bg==3)?(N3):(N4);\
    const int4* tb = tbl + (size_t)nSel * TBL_STRIDE_I4;                     \
    Y0 = tb[ph*2 + 0]; Y1 = tb[ph*2 + 1];                                    \
    X0 = tb[NS + pw*2 + 0]; X1 = tb[NS + pw*2 + 1];                          \
}

#define COMPUTE(CNT,N0,N1,N2,N3,N4, Y0,Y1,X0,X1) {                           \
    float mres = -INFINITY;                                                  \
    _Pragma("unroll")                                                        \
    for (int sy = 0; sy < 2; ++sy) {                                         \
        const int4 yr = sy ? (Y1) : (Y0);                                    \
        const int   yy = yr.x;                                               \
        const float hy = __int_as_float(yr.y), ly = __int_as_float(yr.z);    \
        const int ra = (yy & 63) * Wc;                                       \
        const int rb = (min(yy + 1, Hc - 1) & 63) * Wc;                      \
        _Pragma("unroll")                                                    \
        for (int sx = 0; sx < 2; ++sx) {                                     \
            const int4 xr = sx ? (X1) : (X0);                                \
            const int   xx = xr.x;                                           \
            const float hx = __int_as_float(xr.y), lx = __int_as_float(xr.z);\
            const int cb = min(xx + 1, Wc - 1);                              \
            const float v00 = ring[ra + xx], v01 = ring[ra + cb];            \
            const float v10 = ring[rb + xx], v11 = ring[rb + cb];            \
            const float s = hy*hx*v00 + hy*lx*v01 + ly*hx*v10 + ly*lx*v11;   \
            mres = fmaxf(mres, s);                                           \
        }                                                                    \
    }                                                                        \
    if (hasCell && bg < (CNT)) {                                             \
        const int nS = (bg==0)?(N0):(bg==1)?(N1):(bg==2)?(N2):(bg==3)?(N3):(N4);\
        out[(size_t)nS * PER_BOX + (size_t)c * CELLS + cell] = mres;         \
    }                                                                        \
}

    // ---- prologue ----
    COLLECT(cntA, yfA, tmA, nA0, nA1, nA2, nA3, nA4);
    if (cntA == 0) return;
    {
        const int tgt = min(yfA + WIN, Hc);          // covers tmA (<= yfA+WIN)
        ISSUE(0, tgt); loadedT = tgt;
    }
    LOADREC(nA0, nA1, nA2, nA3, nA4, ya0, ya1, xa0, xa1);
    __syncthreads();                                 // drains vmcnt(0)

    // ---- group loop: collect/issue/recs for B, compute A, barrier ----
    while (cntA) {
        COLLECT(cntB, yfB, tmB, nB0, nB1, nB2, nB3, nB4);
        if (cntB) {
            const int tgt = min(yfA + WIN, Hc);      // eviction-safe vs A
            if (tgt > loadedT) { ISSUE(loadedT, tgt); loadedT = tgt; }
            LOADREC(nB0, nB1, nB2, nB3, nB4, yb0, yb1, xb0, xb1);
        }
        COMPUTE(cntA, nA0, nA1, nA2, nA3, nA4, ya0, ya1, xa0, xa1);
        __syncthreads();                             // B's rows/recs landed
        if (cntB && tmB > loadedT) {                 // y-jump remainder
            ISSUE(loadedT, tmB); loadedT = tmB;
            __syncthreads();
        }
        cntA = cntB; yfA = yfB; tmA = tmB;
        nA0 = nB0; nA1 = nB1; nA2 = nB2; nA3 = nB3; nA4 = nB4;
        ya0 = yb0; ya1 = yb1; xa0 = xb0; xa1 = xb1;
    }

#undef COLLECT
#undef ISSUE
#undef LOADREC
#undef COMPUTE
}

// ============== fallback: R9 kernel (no workspace needed) =============
constexpr int FCG = 4, FTILES = Cc/FCG, FNSAMP = 14;
constexpr int FGRP = 264, FCH_F = 7*FGRP, FBUF_F = FCG*FCH_F;

__global__ __launch_bounds__(256) void roi_fallback_kernel(
    const float* __restrict__ feature, const float* __restrict__ boxes,
    const int* __restrict__ batch_idx, float* __restrict__ out)
{
    __shared__ float lds[2*FBUF_F];
    const int n = blockIdx.x, tid = threadIdx.x;
    const int wvv = tid >> 6, lane = tid & 63;
    const int lane16 = lane & 15, rquad = lane >> 4;

    const float rsx = boxes[n*4+0]*SS, rsy = boxes[n*4+1]*SS;
    const float rex = boxes[n*4+2]*SS, rey = boxes[n*4+3]*SS;
    const float bin_w = fmaxf(rex-rsx,1.f)/7.f, bin_h = fmaxf(rey-rsy,1.f)/7.f;
    const int b = batch_idx[n];
    const float xc0 = fminf(fmaxf(__fadd_rn(rsx,__fmul_rn(0.25f,bin_w)),0.f),(float)(Wc-1));
    const int xbase = ((int)floorf(xc0)) & ~3;
    const float xlc = fminf(fmaxf(__fadd_rn(rsx,__fmul_rn(6.75f,bin_w)),0.f),(float)(Wc-1));
    const int span = min((int)floorf(xlc)+1, Wc-1) - xbase + 1;
    const int nl4 = (span + 4) >> 2;

    int ro[7];
    #pragma unroll
    for (int it = 0; it < 7; ++it) {
        const int slot = it*4 + rquad;
        const int which = slot >= FNSAMP;
        const int sY = which ? slot - FNSAMP : slot;
        const float fy = __fadd_rn(rsy, __fmul_rn(fmaf((float)sY,0.5f,0.25f), bin_h));
        const float fyc = fminf(fmaxf(fy,0.f),(float)(Hc-1));
        const int y0 = (int)floorf(fyc);
        ro[it] = (which ? min(y0+1,Hc-1) : y0) * Wc;
    }
    const int col = min(xbase + lane16*4, Wc-4);
    const bool act = (lane16 < nl4);
    const int cell = min(lane, CELLS-1);
    const int ph = cell/POOLED, pw = cell - ph*POOLED;

    float w00[2][2], w01[2][2], w10[2][2], w11[2][2];
    int r0a[2][2], r1a[2][2];
    #pragma unroll
    for (int sy = 0; sy < 2; ++sy) {
        const int sY = ph*2+sy;
        const float fy = __fadd_rn(rsy, __fmul_rn((float)ph + ((float)sy+0.5f)*0.5f, bin_h));
        const bool vy = (fy>-1.f)&&(fy<(float)Hc);
        const float fyc = fminf(fmaxf(fy,0.f),(float)(Hc-1));
        const int y0i = (int)floorf(fyc);
        const float ly = fyc-(float)y0i, hy = 1.f-ly;
        #pragma unroll
        for (int sx = 0; sx < 2; ++sx) {
            const float fx = __fadd_rn(rsx, __fmul_rn((float)pw + ((float)sx+0.5f)*0.5f, bin_w));
            const bool vx = (fx>-1.f)&&(fx<(float)Wc);
            const float fxc = fminf(fmaxf(fx,0.f),(float)(Wc-1));
            const int x0i = (int)floorf(fxc);
            const float lx = fxc-(float)x0i, hx = 1.f-lx;
            const int c0 = x0i - xbase;
            const bool v = vy && vx;
            w00[sy][sx] = v ? hy*hx : 0.f; w01[sy][sx] = v ? hy*lx : 0.f;
            w10[sy][sx] = v ? ly*hx : 0.f; w11[sy][sx] = v ? ly*lx : 0.f;
            r0a[sy][sx] = (sY>>2)*FGRP + (sY&3)*64 + c0;
            const int s1 = FNSAMP + sY;
            r1a[sy][sx] = (s1>>2)*FGRP + (s1&3)*64 + c0;
        }
    }
    const float* __restrict__ gp0 = feature + ((size_t)b*Cc + wvv)*(size_t)PLANE;

#define FISSUE(GT, Q)                                                         \
    if (act) {                                                                \
        _Pragma("unroll")                                                     \
        for (int it = 0; it < 7; ++it) {                                      \
            const float* gsrc = (GT) + ro[it] + col;                          \
            const int lofs = __builtin_amdgcn_readfirstlane(                  \
                ((Q)*FBUF_F + wvv*FCH_F + it*FGRP)*4);                        \
            __builtin_amdgcn_global_load_lds(                                 \
                (const __attribute__((address_space(1))) unsigned int*)       \
                    (const void*)gsrc,                                        \
                (__attribute__((address_space(3))) unsigned int*)             \
                    (void*)((char*)lds + lofs), 16, 0, 0);                    \
        }                                                                     \
    }

    FISSUE(gp0, 0)
    const float* __restrict__ gnext = gp0 + (size_t)FCG*PLANE;
    for (int j = 0; j < FTILES; ++j) {
        if (j + 1 < FTILES) {
            FISSUE(gnext, ((j+1)&1))
            gnext += (size_t)FCG*PLANE;
            asm volatile("s_waitcnt vmcnt(7)" ::: "memory");
        } else {
            asm volatile("s_waitcnt vmcnt(0)" ::: "memory");
        }
        const int qb = (j&1)*FBUF_F + wvv*FCH_F;
        float m = -INFINITY;
        #pragma unroll
        for (int sy = 0; sy < 2; ++sy)
            #pragma unroll
            for (int sx = 0; sx < 2; ++sx) {
                const int a0 = qb + r0a[sy][sx], a1 = qb + r1a[sy][sx];
                const float bil = w00[sy][sx]*lds[a0] + w01[sy][sx]*lds[a0+1]
                                + w10[sy][sx]*lds[a1] + w11[sy][sx]*lds[a1+1];
                m = fmaxf(m, bil);
            }
        if (lane < CELLS)
            out[(size_t)n*PER_BOX + (size_t)(j*FCG + wvv)*CELLS + cell] = m;
    }
#undef FISSUE
}

extern "C" void kernel_launch(void* const* d_in, const int* in_sizes, int n_in,
                              void* d_out, int out_size, void* d_ws, size_t ws_size,
                              hipStream_t stream) {
    const float* feature   = (const float*)d_in[0];
    const float* boxes     = (const float*)d_in[1];
    const int*   batch_idx = (const int*)d_in[2];
    float*       out       = (float*)d_out;

    if (d_ws != nullptr && ws_size >= WS_NEED) {
        unsigned int* meta = (unsigned int*)d_ws;
        int4* tbl = (int4*)((char*)d_ws + TBL_OFF_B);
        roi_prep_kernel<<<Nc, 64, 0, stream>>>(boxes, batch_idx, meta, tbl);
        roi_stream_kernel<<<Nc, 256, 0, stream>>>(feature, meta, tbl, out);
    } else {
        roi_fallback_kernel<<<Nc, 256, 0, stream>>>(feature, boxes,
                                                    batch_idx, out);
    }
}

// Round 10
// 246.772 us; speedup vs baseline: 1.1360x; 1.1360x over previous
//
#include <hip/hip_runtime.h>

// ROI Align (max) — R13: ph-split waves + depth-5 async pipeline.
//
// R12 post-mortem: plane-streaming got FETCH to 61.8 MB but serialized into
// ~55 barrier-paced groups -> 145 us. Reverted to R9/R10 family.
// R10 analysis: 85.2 us = 3190 cy/iter vs ~250 cy of work -> each wave's
// 64-iter chain is latency-bound at depth-1 prefetch, and with all 512
// blocks co-resident, wall time = 64 x uncovered-latency regardless of
// occupancy. Only pipeline DEPTH helps. Also vmcnt(7) provably drained the
// previous store's ack every iter (it sits between load groups in FIFO).
//
// R13: 8 waves/block, wave-pair per channel: role A = ph0-3 (16 slots,
// NI=4 DMA instrs/tile), role B = ph4-6 (12 slots, NI=3). Per-buffer LDS
// halves -> depth-5 buffers fit: 4ch x 5 x (1040+780)x4B = 145,600 B,
// 1 block/CU. Iter: issue tile t+4; s_waitcnt vmcnt(4*NI) -- FIFO proof:
// newest 16 (A) = loads(t+2..t+4) + 3 stores + 1 of loads(t+1), so tile
// t's loads are always drained and only >=4-iter-old stores are waited.
// Tail (t>=60): vmcnt(0). Slot->group map it=ls>>2, rq=ls&3 with GRP=260
// floats -> read banks {0,0,4,4}-ish = 2-way (free), and consecutive
// samples share a DMA instr (L1 merge for dense boxes).
// Box->XCD perm (R10) kept: n = perm[(bid&7)*64 + bid>>3].
//
// feature: (2, 256, 200, 304) fp32; boxes: (512,4); batch_idx: (512,) i32
// out: (512, 256, 7, 7) fp32. SPATIAL_SCALE=0.25, POOLED=7, SR=2, MODE=max.

#define SS 0.25f
#define POOLED 7

constexpr int Cc = 256;
constexpr int Hc = 200;
constexpr int Wc = 304;
constexpr int Nc = 512;

constexpr int CELLS   = 49;
constexpr int PER_BOX = Cc * CELLS;      // 12544
constexpr int PLANE   = Hc * Wc;         // 60800
constexpr int NSAMP   = 14;
constexpr int TILES   = Cc / 4;          // 64 tiles of 4 channels
constexpr int DEPTH   = 5;
constexpr int GRPF    = 260;             // floats per 4-slot group (1040 B)
constexpr int BUF_A   = 4 * GRPF;        // 1040 floats per buffer (role A)
constexpr int BUF_B   = 3 * GRPF;        // 780  floats per buffer (role B)
constexpr int WAVE_A  = DEPTH * BUF_A;   // 5200 floats
constexpr int WAVE_B  = DEPTH * BUF_B;   // 3900 floats
constexpr int CH_F    = WAVE_A + WAVE_B; // 9100 floats per channel
constexpr int LDS_F   = 4 * CH_F;        // 36400 floats = 145,600 B -> 1 blk/CU
constexpr size_t WS_NEED = (size_t)Nc * sizeof(int);

// ====================== box spatial-rank kernel ======================
// Bijective perm sorted by (batch, y-band, index) -> XCD clustering (R10).
__global__ __launch_bounds__(64) void box_rank_kernel(
    const float* __restrict__ boxes,
    const int*   __restrict__ batch_idx,
    int*         __restrict__ perm)
{
    const int n = blockIdx.x;
    const int l = threadIdx.x;

    const float cyn  = (boxes[n * 4 + 1] + boxes[n * 4 + 3]) * (0.5f * SS);
    const int  bandn = min(3, max(0, (int)(cyn * (4.0f / (float)Hc))));
    const int  keyn  = batch_idx[n] * 4 + bandn;

    int rank = 0;
    #pragma unroll
    for (int m = 0; m < Nc / 64; ++m) {
        const int j = m * 64 + l;
        const float cyj  = (boxes[j * 4 + 1] + boxes[j * 4 + 3]) * (0.5f * SS);
        const int  bandj = min(3, max(0, (int)(cyj * (4.0f / (float)Hc))));
        const int  keyj  = batch_idx[j] * 4 + bandj;
        const bool lt = (keyj < keyn) || (keyj == keyn && j < n);
        rank += (int)__popcll(__ballot(lt));
    }
    if (l == 0) perm[rank] = n;
}

// ============================== main =================================
template <bool USE_PERM>
__global__ __launch_bounds__(512) void roi_align_max_kernel(
    const float* __restrict__ feature,
    const float* __restrict__ boxes,
    const int*   __restrict__ batch_idx,
    const int*   __restrict__ perm,
    float*       __restrict__ out)
{
    __shared__ float lds[LDS_F];         // 145,600 B (gfx950: 160 KB/CU)

    const int bid = blockIdx.x;
    const int n = USE_PERM ? perm[(bid & 7) * 64 + (bid >> 3)] : bid;
    const int tid  = threadIdx.x;
    const int wv   = tid >> 6;
    const int lane = tid & 63;
    const int chl  = wv >> 1;            // channel-local 0..3
    const int role = wv & 1;             // 0 = ph0-3 (A), 1 = ph4-6 (B)
    const int NI    = role ? 3 : 4;      // DMA instrs per tile
    const int BUF   = role ? BUF_B : BUF_A;
    const int wbase = chl * CH_F + (role ? WAVE_A : 0);
    const int HALF  = role ? 6 : 8;      // y0 slot count
    const int SYB   = role ? 8 : 0;      // first sample-y handled
    const int NCELL = role ? 21 : 28;
    const int lane16 = lane & 15;
    const int rquad  = lane >> 4;

    // ---- box math (block-uniform -> scalar) ----
    const float rsx = boxes[n * 4 + 0] * SS;
    const float rsy = boxes[n * 4 + 1] * SS;
    const float rex = boxes[n * 4 + 2] * SS;
    const float rey = boxes[n * 4 + 3] * SS;
    const float roi_w = fmaxf(rex - rsx, 1.0f);
    const float roi_h = fmaxf(rey - rsy, 1.0f);
    const float bin_w = roi_w / (float)POOLED;
    const float bin_h = roi_h / (float)POOLED;
    const int   b     = batch_idx[n];

    const float x_first = __fadd_rn(rsx, __fmul_rn(0.25f, bin_w));
    const float xc0     = fminf(fmaxf(x_first, 0.0f), (float)(Wc - 1));
    const int   xbase   = ((int)floorf(xc0)) & ~3;

    const float x_last = __fadd_rn(rsx, __fmul_rn(6.75f, bin_w));
    const float xlc    = fminf(fmaxf(x_last, 0.0f), (float)(Wc - 1));
    const int   x0l    = (int)floorf(xlc);
    const int   xlastc = min(x0l + 1, Wc - 1);
    const int   span   = xlastc - xbase + 1;      // <= 54
    const int   nl4    = (span + 4) >> 2;         // <= 14 float4 lanes

    // ---- staging rows: DMA instr i writes slots ls = 4i+rq, rq = lane>>4 ----
    // slot ls < HALF: y0 row of sample SYB+ls; ls >= HALF: y1 row.
    int ro[4];
    #pragma unroll
    for (int i = 0; i < 4; ++i) {
        const int ls    = i * 4 + rquad;
        const int which = ls >= HALF;
        const int sY    = SYB + (which ? ls - HALF : ls);
        const float py  = fmaf((float)sY, 0.5f, 0.25f);
        const float fy  = __fadd_rn(rsy, __fmul_rn(py, bin_h));
        const float fyc = fminf(fmaxf(fy, 0.0f), (float)(Hc - 1));
        const int   y0  = (int)floorf(fyc);
        ro[i] = (which ? min(y0 + 1, Hc - 1) : y0) * Wc;
    }
    const int  col = min(xbase + lane16 * 4, Wc - 4);
    const bool act = (lane16 < nl4);

    // ---- compute metadata: lane -> cell within this role's ph range ----
    const int cidx = min(lane, NCELL - 1);
    const int ph   = (role ? 4 : 0) + cidx / 7;
    const int pw   = cidx % 7;

    float w00[2][2], w01[2][2], w10[2][2], w11[2][2];
    int   a0t[2][2], a1t[2][2];          // buffer-relative float offsets
    #pragma unroll
    for (int sy = 0; sy < 2; ++sy) {
        const int   sY  = ph * 2 + sy;
        const float py  = (float)ph + ((float)sy + 0.5f) * 0.5f;
        const float fy  = __fadd_rn(rsy, __fmul_rn(py, bin_h));
        const bool  vy  = (fy > -1.0f) && (fy < (float)Hc);
        const float fyc = fminf(fmaxf(fy, 0.0f), (float)(Hc - 1));
        const int   y0i = (int)floorf(fyc);
        const float ly  = fyc - (float)y0i;
        const float hy  = 1.0f - ly;
        #pragma unroll
        for (int sx = 0; sx < 2; ++sx) {
            const float px  = (float)pw + ((float)sx + 0.5f) * 0.5f;
            const float fx  = __fadd_rn(rsx, __fmul_rn(px, bin_w));
            const bool  vx  = (fx > -1.0f) && (fx < (float)Wc);
            const float fxc = fminf(fmaxf(fx, 0.0f), (float)(Wc - 1));
            const int   x0i = (int)floorf(fxc);
            const float lx  = fxc - (float)x0i;
            const float hx  = 1.0f - lx;
            const int   c0  = x0i - xbase;
            const bool  v   = vy && vx;          // validity folded into weights
            w00[sy][sx] = v ? hy * hx : 0.0f;
            w01[sy][sx] = v ? hy * lx : 0.0f;
            w10[sy][sx] = v ? ly * hx : 0.0f;
            w11[sy][sx] = v ? ly * lx : 0.0f;
            const int lsY = sY - SYB;            // 0..HALF-1
            const int ls0 = lsY;                 // y0 slot
            const int ls1 = lsY + HALF;          // y1 slot
            a0t[sy][sx] = (ls0 >> 2) * GRPF + (ls0 & 3) * 64 + c0;
            a1t[sy][sx] = (ls1 >> 2) * GRPF + (ls1 & 3) * 64 + c0;
        }
    }

#define ISSUE(PTR, QOFF)                                                      \
    if (act) {                                                                \
        for (int i = 0; i < NI; ++i) {                                        \
            const float* gsrc = (PTR) + ro[i] + col;                          \
            const int lofs = __builtin_amdgcn_readfirstlane(                  \
                (wbase + (QOFF) + i * GRPF) * 4);                             \
            __builtin_amdgcn_global_load_lds(                                 \
                (const __attribute__((address_space(1))) unsigned int*)       \
                    (const void*)gsrc,                                        \
                (__attribute__((address_space(3))) unsigned int*)             \
                    (void*)((char*)lds + lofs),                               \
                16, 0, 0);                                                    \
        }                                                                     \
    }

    // ---- prologue: tiles 0..3 -> buffers q = 0..3 ----
    const float* gp0 = feature + ((size_t)b * Cc + chl) * (size_t)PLANE;
    {
        const float* gpt = gp0;
        #pragma unroll
        for (int tt = 0; tt < 4; ++tt) {
            ISSUE(gpt, tt * BUF)
            gpt += (size_t)4 * PLANE;
        }
    }
    const float* gIss = gp0 + (size_t)16 * PLANE;  // tile 4 base
    int qI = 4 * BUF;                    // issue buffer offset (mod DEPTH*BUF)
    int qC = 0;                          // compute buffer offset
    const int QMAX = DEPTH * BUF;
    float* outp = out + (size_t)n * PER_BOX + chl * CELLS
                + (role ? 28 : 0) + cidx;

    // ---- pipelined tile loop (no __syncthreads anywhere) ----
    for (int t = 0; t < TILES; ++t) {
        if (t < TILES - 4) {
            ISSUE(gIss, qI)
            gIss += (size_t)4 * PLANE;
            qI += BUF; if (qI == QMAX) qI = 0;
            // Wait vmcnt(4*NI): newest 4*NI entries are always a subset of
            // {loads(t+1..t+4), stores(t-1..t-3)} -> tile t's loads drained;
            // only >=4-iter-old store acks ever waited on.
            if (role == 0) asm volatile("s_waitcnt vmcnt(16)" ::: "memory");
            else           asm volatile("s_waitcnt vmcnt(12)" ::: "memory");
        } else {
            asm volatile("s_waitcnt vmcnt(0)" ::: "memory");
        }

        const int qb = wbase + qC;
        float m = -INFINITY;
        #pragma unroll
        for (int sy = 0; sy < 2; ++sy) {
            #pragma unroll
            for (int sx = 0; sx < 2; ++sx) {
                const int a0 = qb + a0t[sy][sx];
                const int a1 = qb + a1t[sy][sx];
                const float bil = w00[sy][sx] * lds[a0]
                                + w01[sy][sx] * lds[a0 + 1]
                                + w10[sy][sx] * lds[a1]
                                + w11[sy][sx] * lds[a1 + 1];
                m = fmaxf(m, bil);
            }
        }
        if (lane < NCELL) *outp = m;
        outp += 4 * CELLS;               // next tile: channel += 4
        qC += BUF; if (qC == QMAX) qC = 0;
    }
#undef ISSUE
}

extern "C" void kernel_launch(void* const* d_in, const int* in_sizes, int n_in,
                              void* d_out, int out_size, void* d_ws, size_t ws_size,
                              hipStream_t stream) {
    const float* feature   = (const float*)d_in[0];
    const float* boxes     = (const float*)d_in[1];
    const int*   batch_idx = (const int*)d_in[2];
    float*       out       = (float*)d_out;

    if (d_ws != nullptr && ws_size >= WS_NEED) {
        int* perm = (int*)d_ws;
        box_rank_kernel<<<Nc, 64, 0, stream>>>(boxes, batch_idx, perm);
        roi_align_max_kernel<true><<<Nc, 512, 0, stream>>>(
            feature, boxes, batch_idx, perm, out);
    } else {
        roi_align_max_kernel<false><<<Nc, 512, 0, stream>>>(
            feature, boxes, batch_idx, nullptr, out);
    }
}